// Round 9
// baseline (1655.299 us; speedup 1.0000x reference)
//
#include <hip/hip_runtime.h>
#include <hip/hip_fp16.h>

#define NE      4194304
#define NN      131072
#define NBINS   512        // dst bins of 256 nodes
#define NPB     256
#define CAP     8704       // slots per dst bin: mean 8192 + 5.7 sigma
#define NGRP    8          // XCD groups (dst bins 64 per group)
#define NSLAB   16         // src slabs of 8192 nodes for deg
#define SLABN   8192
#define QPS     16         // blocks per slab
#define CHUNK   16384      // edges per binD block
#define LCAP    3072       // owned-edge LDS list capacity (mean 2048 + 24 sigma)

// ---------------- k_mlp: ew_h[e] = fp16(sigmoid MLP(ea[e])) ----------------
__global__ __launch_bounds__(256) void k_mlp(
    const float* __restrict__ ea,
    const float* __restrict__ w1, const float* __restrict__ b1,
    const float* __restrict__ w2, const float* __restrict__ b2,
    __half* __restrict__ ewh)
{
    __shared__ float s[321];
    for (int i = threadIdx.x; i < 321; i += 256) {
        float v;
        if (i < 256) v = w1[i];
        else if (i < 288) v = b1[i - 256];
        else if (i < 320) v = w2[i - 288];
        else v = b2[0];
        s[i] = v;
    }
    __syncthreads();
    const int e0 = blockIdx.x * 1024 + threadIdx.x;
#pragma unroll
    for (int r = 0; r < 4; ++r) {
        const int e = e0 + r * 256;
        const float4 a0 = ((const float4*)ea)[e * 2 + 0];
        const float4 a1 = ((const float4*)ea)[e * 2 + 1];
        const float av[8] = {a0.x, a0.y, a0.z, a0.w, a1.x, a1.y, a1.z, a1.w};
        float acc = s[320];
#pragma unroll
        for (int j = 0; j < 32; ++j) {
            float h = s[256 + j];
#pragma unroll
            for (int k = 0; k < 8; ++k) h = fmaf(av[k], s[k * 32 + j], h);
            h = fmaxf(h, 0.0f);
            acc = fmaf(h, s[288 + j], acc);
        }
        ewh[e] = __float2half_rn(1.0f / (1.0f + expf(-acc)));
    }
}

// ---------------- k_xh: x -> fp16 ----------------
__global__ __launch_bounds__(256) void k_xh(
    const float* __restrict__ x, __half2* __restrict__ xh)
{
    const int i = blockIdx.x * 256 + threadIdx.x; // 8 floats per thread
    const float4 a = ((const float4*)x)[i * 2 + 0];
    const float4 b = ((const float4*)x)[i * 2 + 1];
    xh[i * 4 + 0] = __floats2half2_rn(a.x, a.y);
    xh[i * 4 + 1] = __floats2half2_rn(a.z, a.w);
    xh[i * 4 + 2] = __floats2half2_rn(b.x, b.y);
    xh[i * 4 + 3] = __floats2half2_rn(b.z, b.w);
}

// ---------------- k_deg_part: per-slab LDS deg accumulation ----------------
// block = slab (16) x q (16): scans edge chunk q, accumulates ew for srcs in
// its slab into LDS, writes non-atomic partial.
__global__ __launch_bounds__(256) void k_deg_part(
    const int* __restrict__ ei, const __half* __restrict__ ewh,
    float* __restrict__ pdeg)
{
    __shared__ float sdeg[SLABN];
    const int slab = blockIdx.x & (NSLAB - 1);
    const int q = blockIdx.x >> 4;
    for (int i = threadIdx.x; i < SLABN; i += 256) sdeg[i] = 0.0f;
    __syncthreads();
    const int lo = slab * SLABN;
    const int chunk = NE / QPS;
    const int e0 = q * chunk;
    for (int i = threadIdx.x; i < chunk; i += 256) {
        const int src = ei[e0 + i];
        const unsigned int l = (unsigned int)(src - lo);
        if (l < SLABN)
            atomicAdd(&sdeg[l], __half2float(ewh[e0 + i]));
    }
    __syncthreads();
    float* dst = pdeg + ((size_t)slab * QPS + q) * SLABN;
    for (int i = threadIdx.x; i < SLABN; i += 256) dst[i] = sdeg[i];
}

// ---------------- k_dinv: reduce partials -> dinv ----------------
__global__ __launch_bounds__(256) void k_dinv(
    const float* __restrict__ pdeg, float* __restrict__ dinv)
{
    const int n = blockIdx.x * 256 + threadIdx.x;
    const int slab = n >> 13;
    const int l = n & (SLABN - 1);
    const float* p = pdeg + (size_t)slab * QPS * SLABN + l;
    float d = 0.0f;
#pragma unroll
    for (int q = 0; q < QPS; ++q) d += p[q * SLABN];
    dinv[n] = (d > 0.0f) ? rsqrtf(d) : 0.0f;
}

// ---------------- k_binD: XCD-grouped dst binning, w folded ----------------
// group g handles dst bins [g*64, g*64+64). payD entry: (src | dl<<17, w)
// with w = -ew * dinv[src] * dinv[dst] fully folded.
__global__ __launch_bounds__(256) void k_binD(
    const int* __restrict__ ei, const __half* __restrict__ ewh,
    const float* __restrict__ dinv,
    int* __restrict__ gCur, int2* __restrict__ payD)
{
    __shared__ int hist[64];
    __shared__ int nOwn;
    __shared__ unsigned short lbuf[LCAP];
    const int g = blockIdx.x & 7;
    const int q = blockIdx.x >> 3;
    if (threadIdx.x < 64) hist[threadIdx.x] = 0;
    if (threadIdx.x == 0) nOwn = 0;
    __syncthreads();
    const int e0 = q * CHUNK;
    for (int i = threadIdx.x; i < CHUNK; i += 256) {
        const int d = ei[NE + e0 + i];
        if ((d >> 14) == g) {
            atomicAdd(&hist[(d >> 8) & 63], 1);
            const int j = atomicAdd(&nOwn, 1);
            if (j < LCAP) lbuf[j] = (unsigned short)i;
        }
    }
    __syncthreads();
    if (threadIdx.x < 64) {
        const int c = hist[threadIdx.x];
        hist[threadIdx.x] = c ? atomicAdd(&gCur[g * 64 + threadIdx.x], c) : 0;
    }
    __syncthreads();
    int m = nOwn;
    if (m > LCAP) m = LCAP;
    for (int j = threadIdx.x; j < m; j += 256) {
        const int e = e0 + lbuf[j];
        const int src = ei[e];
        const int d = ei[NE + e];
        const int bl = (d >> 8) & 63;
        const float w = -__half2float(ewh[e]) * dinv[src] * dinv[d];
        const int p = atomicAdd(&hist[bl], 1);
        if (p < CAP)
            payD[(size_t)(g * 64 + bl) * CAP + p] =
                make_int2(src | ((d & 255) << 17), __float_as_int(w));
    }
}

// ---------------- k_gather: per (bin, split) LDS accumulate ----------------
__global__ __launch_bounds__(512) void k_gather(
    const int2* __restrict__ payD, const int* __restrict__ gCur,
    const __half2* __restrict__ xh, float* __restrict__ pbuf, const int split)
{
    __shared__ float accf[NPB * 17];
    const int bin = blockIdx.x / split;
    const int s = blockIdx.x - bin * split;
    for (int i = threadIdx.x; i < NPB * 17; i += 512) accf[i] = 0.0f;
    __syncthreads();
    int cnt = gCur[bin];
    if (cnt > CAP) cnt = CAP;
    const int i0 = (int)((long long)cnt * s / split);
    const int i1 = (int)((long long)cnt * (s + 1) / split);
    const int2* p = payD + (size_t)bin * CAP;
    for (int i = i0 + threadIdx.x; i < i1; i += 512) {
        const int2 pl = p[i];
        const int src = pl.x & 0x1FFFF;
        const int dl = (pl.x >> 17) & 255;
        const float w = __int_as_float(pl.y);
        const float4* xp = (const float4*)(xh + (size_t)src * 8);
        float4 A = xp[0], B = xp[1];
        const __half2* ha = (const __half2*)&A;
        const __half2* hb = (const __half2*)&B;
        float* ap = accf + dl * 17;
#pragma unroll
        for (int k = 0; k < 4; ++k) {
            const float2 f = __half22float2(ha[k]);
            atomicAdd(ap + 2 * k,     w * f.x);
            atomicAdd(ap + 2 * k + 1, w * f.y);
        }
#pragma unroll
        for (int k = 0; k < 4; ++k) {
            const float2 f = __half22float2(hb[k]);
            atomicAdd(ap + 8 + 2 * k,     w * f.x);
            atomicAdd(ap + 8 + 2 * k + 1, w * f.y);
        }
    }
    __syncthreads();
    float* dst = pbuf + ((size_t)bin * split + s) * (NPB * 16);
    for (int i = threadIdx.x; i < NPB * 16; i += 512)
        dst[i] = accf[(i >> 4) * 17 + (i & 15)];
}

// ---------------- k_out: reduce partials + GRU epilogue ----------------
__global__ __launch_bounds__(512) void k_out(
    const float* __restrict__ pbuf, const float* __restrict__ x,
    const float* __restrict__ wxz, const float* __restrict__ bxz,
    const float* __restrict__ bhz,
    const float* __restrict__ wxh, const float* __restrict__ bxh,
    const float* __restrict__ bhh,
    float* __restrict__ out, const int split)
{
    __shared__ float swz[1024];
    __shared__ float swh[1024];
    __shared__ float sbz[32], sbh[32];
    for (int i = threadIdx.x; i < 1024; i += 512) {
        swz[i] = wxz[i];
        swh[i] = wxh[i];
    }
    if (threadIdx.x < 32) {
        sbz[threadIdx.x] = bxz[threadIdx.x] + bhz[threadIdx.x];
        sbh[threadIdx.x] = bxh[threadIdx.x] + bhh[threadIdx.x];
    }
    __syncthreads();
    const int b = blockIdx.x;
    const int t = threadIdx.x;
    const int nl = t >> 1;
    const int node = b * NPB + nl;
    const int j0 = (t & 1) * 16;
    float tr[16];
    {
        const float4* p0 = (const float4*)(pbuf + ((size_t)b * split) * (NPB * 16) + nl * 16);
        float4 a0 = p0[0], a1 = p0[1], a2 = p0[2], a3 = p0[3];
        tr[0] = a0.x;  tr[1] = a0.y;  tr[2] = a0.z;  tr[3] = a0.w;
        tr[4] = a1.x;  tr[5] = a1.y;  tr[6] = a1.z;  tr[7] = a1.w;
        tr[8] = a2.x;  tr[9] = a2.y;  tr[10] = a2.z; tr[11] = a2.w;
        tr[12] = a3.x; tr[13] = a3.y; tr[14] = a3.z; tr[15] = a3.w;
        for (int s = 1; s < split; ++s) {
            const float4* ps = (const float4*)(pbuf + ((size_t)b * split + s) * (NPB * 16) + nl * 16);
            const float4 c0 = ps[0], c1 = ps[1], c2 = ps[2], c3 = ps[3];
            tr[0] += c0.x;  tr[1] += c0.y;  tr[2] += c0.z;  tr[3] += c0.w;
            tr[4] += c1.x;  tr[5] += c1.y;  tr[6] += c1.z;  tr[7] += c1.w;
            tr[8] += c2.x;  tr[9] += c2.y;  tr[10] += c2.z; tr[11] += c2.w;
            tr[12] += c3.x; tr[13] += c3.y; tr[14] += c3.z; tr[15] += c3.w;
        }
    }
    float xr[16];
    {
        const float4* xp = (const float4*)(x + (size_t)node * 16);
#pragma unroll
        for (int q = 0; q < 4; ++q) {
            const float4 a = xp[q];
            xr[q * 4 + 0] = a.x; xr[q * 4 + 1] = a.y;
            xr[q * 4 + 2] = a.z; xr[q * 4 + 3] = a.w;
        }
    }
    float o[16];
#pragma unroll
    for (int jj = 0; jj < 16; ++jj) {
        const int j = j0 + jj;
        float az = sbz[j];
        float ah = sbh[j];
#pragma unroll
        for (int k = 0; k < 16; ++k) {
            az = fmaf(xr[k], swz[k * 32 + j], az);
            az = fmaf(tr[k], swz[512 + k * 32 + j], az);
            ah = fmaf(xr[k], swh[k * 32 + j], ah);
            ah = fmaf(tr[k], swh[512 + k * 32 + j], ah);
        }
        const float z = 1.0f / (1.0f + expf(-az));
        o[jj] = (1.0f - z) * tanhf(ah);
    }
    float4* op = (float4*)(out + (size_t)node * 32 + j0);
#pragma unroll
    for (int q = 0; q < 4; ++q)
        op[q] = make_float4(o[q * 4 + 0], o[q * 4 + 1], o[q * 4 + 2], o[q * 4 + 3]);
}

extern "C" void kernel_launch(void* const* d_in, const int* in_sizes, int n_in,
                              void* d_out, int out_size, void* d_ws, size_t ws_size,
                              hipStream_t stream) {
    const float* x   = (const float*)d_in[0];
    const int*   ei  = (const int*)d_in[1];
    const float* ea  = (const float*)d_in[2];
    const float* w1  = (const float*)d_in[3];
    const float* b1  = (const float*)d_in[4];
    const float* w2  = (const float*)d_in[5];
    const float* b2  = (const float*)d_in[6];
    const float* wxz = (const float*)d_in[7];
    const float* bxz = (const float*)d_in[8];
    const float* bhz = (const float*)d_in[10];
    const float* wxh = (const float*)d_in[15];
    const float* bxh = (const float*)d_in[16];
    const float* bhh = (const float*)d_in[18];
    float* out = (float*)d_out;

    // ---- workspace layout (4-byte words) ----
    // [payD 512*CAP int2 = 8,912,896 w]  (head doubles as pdeg 2,097,152 w
    //                                     during the deg phase, disjoint lifetime)
    // [x_h  1,048,576 w][dinv 131,072 w][gCur 512 w]
    // [ew_h 2,097,152 w -> becomes pbuf split 0][extra pbuf splits ...]
    int* wsw = (int*)d_ws;
    int2*    payD = (int2*)wsw;
    float*   pdeg = (float*)wsw;                          // aliases payD head
    __half2* xh   = (__half2*)(wsw + (size_t)2 * NBINS * CAP);
    float*   dinv = (float*)(wsw + (size_t)2 * NBINS * CAP + 1048576);
    int*     gCur = wsw + (size_t)2 * NBINS * CAP + 1048576 + 131072;
    __half*  ewh  = (__half*)(gCur + 512);
    float*   pbuf = (float*)ewh;                          // aliases ew_h region

    const size_t base_words = (size_t)2 * NBINS * CAP + 1048576 + 131072 + 512;
    const size_t rest = ws_size / 4 - base_words;         // words for pbuf
    int split = (int)(rest / 2097152);                    // 8.39 MB per split
    if (split < 1) split = 1;
    if (split > 4) split = 4;

    hipMemsetAsync(gCur, 0, 512 * sizeof(int), stream);

    k_mlp<<<NE / 1024, 256, 0, stream>>>(ea, w1, b1, w2, b2, ewh);
    k_xh<<<1024, 256, 0, stream>>>(x, xh);
    k_deg_part<<<NSLAB * QPS, 256, 0, stream>>>(ei, ewh, pdeg);
    k_dinv<<<NN / 256, 256, 0, stream>>>(pdeg, dinv);
    k_binD<<<(NE / CHUNK) * NGRP, 256, 0, stream>>>(ei, ewh, dinv, gCur, payD);
    k_gather<<<NBINS * split, 512, 0, stream>>>(payD, gCur, xh, pbuf, split);
    k_out<<<NBINS, 512, 0, stream>>>(pbuf, x, wxz, bxz, bhz, wxh, bxh, bhh, out, split);
}

// Round 10
// 1146.477 us; speedup vs baseline: 1.4438x; 1.4438x over previous
//
#include <hip/hip_runtime.h>
#include <hip/hip_fp16.h>

#define NE      4194304
#define NN      131072
#define NBINS   512        // node bins of 256 (both src- and dst-keyed)
#define NPB     256
#define CAP_MAX 8704       // mean 8192 + 5.7 sigma
#define CHUNK   16384      // edges per bin-scan block
#define LCAP    3072       // owned-edge stash (mean 2048 + 24 sigma)

__device__ inline float h2f_bits(unsigned int b) {
    __half_raw r; r.x = (unsigned short)b;
    return __half2float(__half(r));
}

// ---------------- k_mlp: ea -> ewh (fp16 sigmoid MLP) ----------------
__global__ __launch_bounds__(256) void k_mlp(
    const float* __restrict__ ea,
    const float* __restrict__ w1, const float* __restrict__ b1,
    const float* __restrict__ w2, const float* __restrict__ b2,
    __half* __restrict__ ewh)
{
    __shared__ float s[321];
    for (int i = threadIdx.x; i < 321; i += 256) {
        float v;
        if (i < 256) v = w1[i];
        else if (i < 288) v = b1[i - 256];
        else if (i < 320) v = w2[i - 288];
        else v = b2[0];
        s[i] = v;
    }
    __syncthreads();
    const int e0 = blockIdx.x * 1024 + threadIdx.x;
#pragma unroll
    for (int r = 0; r < 4; ++r) {
        const int e = e0 + r * 256;
        const float4 a0 = ((const float4*)ea)[e * 2 + 0];
        const float4 a1 = ((const float4*)ea)[e * 2 + 1];
        const float av[8] = {a0.x, a0.y, a0.z, a0.w, a1.x, a1.y, a1.z, a1.w};
        float acc = s[320];
#pragma unroll
        for (int j = 0; j < 32; ++j) {
            float h = s[256 + j];
#pragma unroll
            for (int k = 0; k < 8; ++k) h = fmaf(av[k], s[k * 32 + j], h);
            h = fmaxf(h, 0.0f);
            acc = fmaf(h, s[288 + j], acc);
        }
        ewh[e] = __float2half_rn(1.0f / (1.0f + expf(-acc)));
    }
}

// ---------------- k_binS: src-binned payload (XCD-affine) ----------------
// group g owns src in [g*16384,(g+1)*16384); payS entry: ewbits<<8 | srclow
__global__ __launch_bounds__(256) void k_binS(
    const int* __restrict__ ei, const __half* __restrict__ ewh,
    int* __restrict__ gCurS, unsigned int* __restrict__ payS, const int cap)
{
    __shared__ int hist[64];
    __shared__ int nOwn;
    __shared__ unsigned int lbuf[LCAP];
    const int g = blockIdx.x & 7;
    const int q = blockIdx.x >> 3;
    if (threadIdx.x < 64) hist[threadIdx.x] = 0;
    if (threadIdx.x == 0) nOwn = 0;
    __syncthreads();
    const int e0 = q * CHUNK;
    const unsigned short* ewb = (const unsigned short*)ewh;
    for (int i = threadIdx.x; i < CHUNK; i += 256) {
        const int src = ei[e0 + i];
        const unsigned int w = ewb[e0 + i];   // streamed coalesced
        if ((src >> 14) == g) {
            const int bl = (src >> 8) & 63;
            atomicAdd(&hist[bl], 1);
            const int j = atomicAdd(&nOwn, 1);
            if (j < LCAP) lbuf[j] = ((unsigned)bl << 24) | (w << 8) | (unsigned)(src & 255);
        }
    }
    __syncthreads();
    if (threadIdx.x < 64) {
        const int c = hist[threadIdx.x];
        hist[threadIdx.x] = c ? atomicAdd(&gCurS[g * 64 + threadIdx.x], c) : 0;
    }
    __syncthreads();
    int m = nOwn;
    if (m > LCAP) m = LCAP;
    for (int j = threadIdx.x; j < m; j += 256) {
        const unsigned int u = lbuf[j];
        const int bl = u >> 24;
        const int p = atomicAdd(&hist[bl], 1);
        if (p < cap) payS[(size_t)(g * 64 + bl) * cap + p] = u & 0x00FFFFFFu;
    }
}

// ---------------- k_degS: per-bin deg reduce -> dinv ----------------
__global__ __launch_bounds__(256) void k_degS(
    const unsigned int* __restrict__ payS, const int* __restrict__ gCurS,
    float* __restrict__ dinv, const int cap)
{
    __shared__ float sdeg[NPB];
    const int bin = (blockIdx.x & 7) * 64 + (blockIdx.x >> 3); // XCD-affine remap
    sdeg[threadIdx.x] = 0.0f;
    __syncthreads();
    int cnt = gCurS[bin];
    if (cnt > cap) cnt = cap;
    const unsigned int* p = payS + (size_t)bin * cap;
    for (int i = threadIdx.x; i < cnt; i += 256) {
        const unsigned int u = p[i];
        atomicAdd(&sdeg[u & 255u], h2f_bits(u >> 8));
    }
    __syncthreads();
    const float d = sdeg[threadIdx.x];
    dinv[bin * NPB + threadIdx.x] = (d > 0.0f) ? rsqrtf(d) : 0.0f;
}

// ---------------- k_binD: dst-binned payload, w fully folded ----------------
// payD entry: (src | dl<<17, w_fp32) with w = -ew*dinv[src]*dinv[dst]
__global__ __launch_bounds__(256) void k_binD(
    const int* __restrict__ ei, const __half* __restrict__ ewh,
    const float* __restrict__ dinv,
    int* __restrict__ gCurD, int2* __restrict__ payD, const int cap)
{
    __shared__ int hist[64];
    __shared__ int nOwn;
    __shared__ unsigned long long lbuf[LCAP]; // src17 | dl8<<17 | bl6<<25 | ew16<<32
    const int g = blockIdx.x & 7;
    const int q = blockIdx.x >> 3;
    if (threadIdx.x < 64) hist[threadIdx.x] = 0;
    if (threadIdx.x == 0) nOwn = 0;
    __syncthreads();
    const int e0 = q * CHUNK;
    const unsigned short* ewb = (const unsigned short*)ewh;
    for (int i = threadIdx.x; i < CHUNK; i += 256) {
        const int src = ei[e0 + i];            // all three streamed coalesced
        const int dst = ei[NE + e0 + i];
        const unsigned int w = ewb[e0 + i];
        if ((dst >> 14) == g) {
            const int bl = (dst >> 8) & 63;
            atomicAdd(&hist[bl], 1);
            const int j = atomicAdd(&nOwn, 1);
            if (j < LCAP)
                lbuf[j] = (unsigned long long)src
                        | ((unsigned long long)(dst & 255) << 17)
                        | ((unsigned long long)bl << 25)
                        | ((unsigned long long)w << 32);
        }
    }
    __syncthreads();
    if (threadIdx.x < 64) {
        const int c = hist[threadIdx.x];
        hist[threadIdx.x] = c ? atomicAdd(&gCurD[g * 64 + threadIdx.x], c) : 0;
    }
    __syncthreads();
    int m = nOwn;
    if (m > LCAP) m = LCAP;
    for (int j = threadIdx.x; j < m; j += 256) {
        const unsigned long long u = lbuf[j];
        const int bl  = (int)((u >> 25) & 63);
        const int src = (int)(u & 0x1FFFF);
        const int dst = (g << 14) | (bl << 8) | (int)((u >> 17) & 255);
        const float w = -h2f_bits((unsigned int)(u >> 32)) * dinv[src] * dinv[dst];
        const int p = atomicAdd(&hist[bl], 1);
        if (p < cap)
            payD[(size_t)(g * 64 + bl) * cap + p] =
                make_int2((int)(u & 0x1FFFFFF), __float_as_int(w));
    }
}

// ---------------- k_xh: x -> fp16 (overlays dead ewh) ----------------
__global__ __launch_bounds__(256) void k_xh(
    const float* __restrict__ x, __half2* __restrict__ xh)
{
    const int i = blockIdx.x * 256 + threadIdx.x; // 8 floats per thread
    const float4 a = ((const float4*)x)[i * 2 + 0];
    const float4 b = ((const float4*)x)[i * 2 + 1];
    xh[i * 4 + 0] = __floats2half2_rn(a.x, a.y);
    xh[i * 4 + 1] = __floats2half2_rn(a.z, a.w);
    xh[i * 4 + 2] = __floats2half2_rn(b.x, b.y);
    xh[i * 4 + 3] = __floats2half2_rn(b.z, b.w);
}

// ---------------- k_gather_out: LDS accumulate + fused GRU epilogue ------
__global__ __launch_bounds__(1024) void k_gather_out(
    const int2* __restrict__ payD, const int* __restrict__ gCurD,
    const __half2* __restrict__ xh, const float* __restrict__ x,
    const float* __restrict__ wxz, const float* __restrict__ bxz,
    const float* __restrict__ bhz,
    const float* __restrict__ wxh, const float* __restrict__ bxh,
    const float* __restrict__ bhh,
    float* __restrict__ out, const int cap)
{
    __shared__ float swz[1024];
    __shared__ float swh[1024];
    __shared__ float sbz[32], sbh[32];
    __shared__ float acc[NPB * 17];
    const int bin = (blockIdx.x & 7) * 64 + (blockIdx.x >> 3); // XCD-affine remap
    const int t = threadIdx.x;
    swz[t] = wxz[t];
    swh[t] = wxh[t];
    if (t < 32) {
        sbz[t] = bxz[t] + bhz[t];
        sbh[t] = bxh[t] + bhh[t];
    }
    for (int i = t; i < NPB * 17; i += 1024) acc[i] = 0.0f;
    __syncthreads();

    int cnt = gCurD[bin];
    if (cnt > cap) cnt = cap;
    const int2* p = payD + (size_t)bin * cap;
    for (int i = t; i < cnt; i += 1024) {
        const int2 pl = p[i];
        const int src = pl.x & 0x1FFFF;
        const int dl  = (pl.x >> 17) & 255;
        const float w = __int_as_float(pl.y);
        const float4* xp = (const float4*)(xh + (size_t)src * 8);
        float4 A = xp[0], B = xp[1];
        const __half2* ha = (const __half2*)&A;
        const __half2* hb = (const __half2*)&B;
        float* ap = acc + dl * 17;
#pragma unroll
        for (int k = 0; k < 4; ++k) {
            const float2 f = __half22float2(ha[k]);
            atomicAdd(ap + 2 * k,     w * f.x);
            atomicAdd(ap + 2 * k + 1, w * f.y);
        }
#pragma unroll
        for (int k = 0; k < 4; ++k) {
            const float2 f = __half22float2(hb[k]);
            atomicAdd(ap + 8 + 2 * k,     w * f.x);
            atomicAdd(ap + 8 + 2 * k + 1, w * f.y);
        }
    }
    __syncthreads();

    // epilogue: thread t -> node bin*256 + (t>>2), output 8-slice j0=(t&3)*8
    const int nl = t >> 2;
    const int node = bin * NPB + nl;
    const int j0 = (t & 3) * 8;
    float tr[16], xr[16];
    const float* ap = acc + nl * 17;
#pragma unroll
    for (int k = 0; k < 16; ++k) tr[k] = ap[k];
    {
        const float4* xp = (const float4*)(x + (size_t)node * 16);
#pragma unroll
        for (int q = 0; q < 4; ++q) {
            const float4 a = xp[q];
            xr[q * 4 + 0] = a.x; xr[q * 4 + 1] = a.y;
            xr[q * 4 + 2] = a.z; xr[q * 4 + 3] = a.w;
        }
    }
    float o[8];
#pragma unroll
    for (int jj = 0; jj < 8; ++jj) {
        const int j = j0 + jj;
        float az = sbz[j];
        float ah = sbh[j];
#pragma unroll
        for (int k = 0; k < 16; ++k) {
            az = fmaf(xr[k], swz[k * 32 + j], az);
            az = fmaf(tr[k], swz[512 + k * 32 + j], az);
            ah = fmaf(xr[k], swh[k * 32 + j], ah);
            ah = fmaf(tr[k], swh[512 + k * 32 + j], ah);
        }
        const float z = 1.0f / (1.0f + expf(-az));
        o[jj] = (1.0f - z) * tanhf(ah);
    }
    float4* op = (float4*)(out + (size_t)node * 32 + j0);
    op[0] = make_float4(o[0], o[1], o[2], o[3]);
    op[1] = make_float4(o[4], o[5], o[6], o[7]);
}

extern "C" void kernel_launch(void* const* d_in, const int* in_sizes, int n_in,
                              void* d_out, int out_size, void* d_ws, size_t ws_size,
                              hipStream_t stream) {
    const float* x   = (const float*)d_in[0];
    const int*   ei  = (const int*)d_in[1];
    const float* ea  = (const float*)d_in[2];
    const float* w1  = (const float*)d_in[3];
    const float* b1  = (const float*)d_in[4];
    const float* w2  = (const float*)d_in[5];
    const float* b2  = (const float*)d_in[6];
    const float* wxz = (const float*)d_in[7];
    const float* bxz = (const float*)d_in[8];
    const float* bhz = (const float*)d_in[10];
    const float* wxh = (const float*)d_in[15];
    const float* bxh = (const float*)d_in[16];
    const float* bhh = (const float*)d_in[18];
    float* out = (float*)d_out;

    // ---- workspace layout (4-byte words) ----
    // [ewh 2,097,152 w  -> xh (1,048,576 w) overlays after k_binD]
    // [dinv 131,072 w][gCurS 512][gCurD 512]
    // [payRegion 1024*cap w : payS (512*cap u32) first, payD (512*cap int2) after]
    int* wsw = (int*)d_ws;
    __half*  ewh  = (__half*)wsw;
    __half2* xh   = (__half2*)wsw;                         // overlays ewh
    float*   dinv = (float*)(wsw + 2097152);
    int*     gCurS = wsw + 2097152 + 131072;
    int*     gCurD = gCurS + 512;
    int*     payBase = gCurD + 512;
    const size_t fixed_words = 2097152 + 131072 + 1024;
    int cap = (int)((ws_size / 4 - fixed_words) / 1024);
    if (cap > CAP_MAX) cap = CAP_MAX;
    unsigned int* payS = (unsigned int*)payBase;           // lifetime: binS..degS
    int2*         payD = (int2*)payBase;                   // lifetime: binD..gather

    hipMemsetAsync(gCurS, 0, 1024 * sizeof(int), stream);

    k_mlp<<<NE / 1024, 256, 0, stream>>>(ea, w1, b1, w2, b2, ewh);
    k_binS<<<(NE / CHUNK) * 8, 256, 0, stream>>>(ei, ewh, gCurS, payS, cap);
    k_degS<<<NBINS, 256, 0, stream>>>(payS, gCurS, dinv, cap);
    k_binD<<<(NE / CHUNK) * 8, 256, 0, stream>>>(ei, ewh, dinv, gCurD, payD, cap);
    k_xh<<<1024, 256, 0, stream>>>(x, xh);
    k_gather_out<<<NBINS, 1024, 0, stream>>>(payD, gCurD, xh, x,
                                             wxz, bxz, bhz, wxh, bxh, bhh, out, cap);
}